// Round 11
// baseline (152.110 us; speedup 1.0000x reference)
//
#include <hip/hip_runtime.h>
#include <stdint.h>

#define PARTITIONABLE 1

typedef float f32x4 __attribute__((ext_vector_type(4)));
typedef short bf16x8 __attribute__((ext_vector_type(8)));

namespace {
constexpr int Hh = 56, Ww = 56;
constexpr int HW = Hh * Ww;            // 3136
constexpr int Bsz = 32, Cch = 256;
constexpr int NCH = 69811;             // ceil(25690112*4/1472)
constexpr int HALF = 34906;
constexpr int NB2 = 4096;              // rank buckets (top 12 bits)

// ---- d_out scratch layout (u32 word offsets; consumed before final write) ----
constexpr int SC1_W   = 0;             // u64 x 69824
constexpr int SC2_W   = 139648;
constexpr int BITS1_W = 279296;
constexpr int BITS2_W = 349120;
constexpr int R1_W    = 418944;
constexpr int R2_W    = 488768;
constexpr int HIST1_W = 558592;        // 4096 each, 6 arrays contiguous
constexpr int PRE1_W  = 562688;
constexpr int CNT1_W  = 566784;
constexpr int HIST2_W = 570880;
constexpr int PRE2_W  = 574976;
constexpr int CNT2_W  = 579072;
constexpr int Y_W     = 583168;        // 8192 floats

// ---- d_ws layout ----
constexpr int KEEP_W  = 0;             // 69824 floats
constexpr int MASKV_W = 69824;         // 8192 floats
constexpr int WPACK_W = 78016;         // then bf16 packed weights (ushort)
}

// ---------------- threefry-2x32 (JAX-compatible) ----------------
__host__ __device__ constexpr uint32_t rotl32(uint32_t v, int r) {
  return (v << r) | (v >> (32 - r));
}
__host__ __device__ constexpr uint64_t tf2x32(uint32_t k0, uint32_t k1,
                                              uint32_t x0, uint32_t x1) {
  uint32_t ks2 = k0 ^ k1 ^ 0x1BD11BDAu;
  x0 += k0; x1 += k1;
  {const int R[4]={13,15,26,6};  for(int i=0;i<4;i++){x0+=x1;x1=rotl32(x1,R[i]);x1^=x0;}}
  x0 += k1;  x1 += ks2 + 1u;
  {const int R[4]={17,29,16,24}; for(int i=0;i<4;i++){x0+=x1;x1=rotl32(x1,R[i]);x1^=x0;}}
  x0 += ks2; x1 += k0 + 2u;
  {const int R[4]={13,15,26,6};  for(int i=0;i<4;i++){x0+=x1;x1=rotl32(x1,R[i]);x1^=x0;}}
  x0 += k0;  x1 += k1 + 3u;
  {const int R[4]={17,29,16,24}; for(int i=0;i<4;i++){x0+=x1;x1=rotl32(x1,R[i]);x1^=x0;}}
  x0 += k1;  x1 += ks2 + 4u;
  {const int R[4]={13,15,26,6};  for(int i=0;i<4;i++){x0+=x1;x1=rotl32(x1,R[i]);x1^=x0;}}
  x0 += ks2; x1 += k0 + 5u;
  return ((uint64_t)x0 << 32) | x1;
}

#if PARTITIONABLE
constexpr uint64_t KEY1 = tf2x32(0u, 1234u, 0u, 0u);
constexpr uint64_t SUB1 = tf2x32(0u, 1234u, 0u, 1u);
constexpr uint64_t SUB2 = tf2x32((uint32_t)(KEY1 >> 32), (uint32_t)KEY1, 0u, 1u);
constexpr uint32_t S1H = (uint32_t)(SUB1 >> 32), S1L = (uint32_t)SUB1;
constexpr uint32_t S2H = (uint32_t)(SUB2 >> 32), S2L = (uint32_t)SUB2;
#else
constexpr uint64_t E0 = tf2x32(0u, 1234u, 0u, 2u);
constexpr uint64_t E1 = tf2x32(0u, 1234u, 1u, 3u);
constexpr uint32_t K1H = (uint32_t)(E0 >> 32), K1L = (uint32_t)(E1 >> 32);
constexpr uint64_t F0 = tf2x32(K1H, K1L, 0u, 2u);
constexpr uint64_t F1 = tf2x32(K1H, K1L, 1u, 3u);
constexpr uint32_t S1H = (uint32_t)E0, S1L = (uint32_t)E1;
constexpr uint32_t S2H = (uint32_t)F0, S2L = (uint32_t)F1;
#endif

__device__ __forceinline__ uint32_t rnd_bits(uint32_t kh, uint32_t kl, uint32_t i) {
#if PARTITIONABLE
  uint64_t r = tf2x32(kh, kl, 0u, i);
  return (uint32_t)(r >> 32) ^ (uint32_t)r;
#else
  if (i < (uint32_t)HALF) {
    uint32_t x1 = (i + HALF < (uint32_t)NCH) ? i + HALF : 0u;
    return (uint32_t)(tf2x32(kh, kl, i, x1) >> 32);
  } else {
    return (uint32_t)tf2x32(kh, kl, i - HALF, i);
  }
#endif
}

// ---------------- bf16 helpers ----------------
__device__ __forceinline__ uint32_t f2bf(float f) {   // manual RNE (wpack path)
  uint32_t u = __float_as_uint(f);
  return (u + 0x7FFFu + ((u >> 16) & 1u)) >> 16;
}
__device__ __forceinline__ float bf2f(uint32_t h) {
  return __uint_as_float(h << 16);
}
// single-instruction packed f32x2 -> bf16x2 (RNE), gfx950
__device__ __forceinline__ uint32_t cvtpk(float lo, float hi) {
  uint32_t r;
  asm("v_cvt_pk_bf16_f32 %0, %1, %2" : "=v"(r) : "v"(lo), "v"(hi));
  return r;
}

// ---------------- mask pipeline ----------------
__global__ void k_bits(uint32_t* bits1, uint32_t* bits2,
                       uint32_t* hist1, uint32_t* hist2) {
  int i = blockIdx.x * 256 + threadIdx.x;
  if (i >= NCH) return;
  uint32_t b1 = rnd_bits(S1H, S1L, (uint32_t)i);
  uint32_t b2 = rnd_bits(S2H, S2L, (uint32_t)i);
  bits1[i] = b1; bits2[i] = b2;
  atomicAdd(&hist1[b1 >> 20], 1u);
  atomicAdd(&hist2[b2 >> 20], 1u);
}

// both scans in one launch: block 0 -> (h1,p1), block 1 -> (h2,p2)
__global__ __launch_bounds__(1024) void k_scan2(const uint32_t* h1, uint32_t* p1o,
                                                const uint32_t* h2, uint32_t* p2o) {
  const uint32_t* h = blockIdx.x ? h2 : h1;
  uint32_t* pre = blockIdx.x ? p2o : p1o;
  __shared__ uint32_t part[1024];
  int t = threadIdx.x;
  uint4 v = *(const uint4*)&h[t * 4];
  uint32_t s = v.x + v.y + v.z + v.w;
  part[t] = s;
  __syncthreads();
  for (int off = 1; off < 1024; off <<= 1) {
    uint32_t u = (t >= off) ? part[t - off] : 0u;
    __syncthreads();
    part[t] += u;
    __syncthreads();
  }
  uint32_t run = part[t] - s;
  uint4 o;
  o.x = run; o.y = run + v.x; o.z = o.y + v.y; o.w = o.z + v.z;
  *(uint4*)&pre[t * 4] = o;
}

__global__ void k_scatter2(const uint32_t* bits1, const uint32_t* pre1,
                           uint32_t* cnt1, uint64_t* sc1,
                           const uint32_t* bits2, const uint32_t* pre2,
                           uint32_t* cnt2, uint64_t* sc2) {
  int blk = blockIdx.x;
  bool second = blk >= 273;
  const uint32_t* bits = second ? bits2 : bits1;
  const uint32_t* pre  = second ? pre2  : pre1;
  uint32_t* cnt = second ? cnt2 : cnt1;
  uint64_t* sc  = second ? sc2  : sc1;
  int i = (second ? blk - 273 : blk) * 256 + threadIdx.x;
  if (i >= NCH) return;
  uint32_t b = bits[i], bk = b >> 20;
  uint32_t pos = pre[bk] + atomicAdd(&cnt[bk], 1u);
  sc[pos] = ((uint64_t)b << 32) | (uint32_t)i;
}

__global__ void k_rank2(const uint32_t* bits1, const uint32_t* pre1,
                        const uint32_t* hist1, const uint64_t* sc1, uint32_t* rk1,
                        const uint32_t* bits2, const uint32_t* pre2,
                        const uint32_t* hist2, const uint64_t* sc2, uint32_t* rk2) {
  int blk = blockIdx.x;
  bool second = blk >= 273;
  const uint32_t* bits = second ? bits2 : bits1;
  const uint32_t* pre  = second ? pre2  : pre1;
  const uint32_t* hist = second ? hist2 : hist1;
  const uint64_t* sc   = second ? sc2   : sc1;
  uint32_t* rnk = second ? rk2 : rk1;
  int i = (second ? blk - 273 : blk) * 256 + threadIdx.x;
  if (i >= NCH) return;
  uint32_t b = bits[i], bk = b >> 20;
  uint32_t s = pre[bk], n = hist[bk];
  uint64_t my = ((uint64_t)b << 32) | (uint32_t)i;
  uint32_t c = 0;
  for (uint32_t k = 0; k < n; ++k) c += (sc[s + k] < my) ? 1u : 0u;
  rnk[i] = s + c;
}

// keep + weight prepack fused (wpack part has no deps on rank)
__global__ void k_keepwpack(const uint32_t* r1, const uint32_t* r2,
                            const int* plr, float* keep,
                            const float* __restrict__ dw,
                            const float* __restrict__ r1w,
                            const float* __restrict__ r2w,
                            ushort* __restrict__ wdp, ushort* __restrict__ w1p,
                            ushort* __restrict__ w2p) {
  int blk = blockIdx.x;
  if (blk < 273) {
    int j = blk * 256 + threadIdx.x;
    if (j >= NCH) return;
    int L = (NCH * plr[0] + 99) / 100;
    keep[j] = (r2[r1[j]] < (uint32_t)L) ? 0.f : 1.f;
    return;
  }
  int tid = (blk - 273) * 256 + threadIdx.x;   // 32768 slots
  const float* src;
  ushort* dst;
  if (tid < 8192) {
    int s = tid, ot = s >> 9, ks = (s >> 6) & 7, l = s & 63;
    src = dw + (ot * 16 + (l & 15)) * 256 + ks * 32 + (l >> 4) * 8;
    dst = wdp + s * 8;
  } else if (tid < 24576) {
    int s = tid - 8192, ot = s >> 10, ks = (s >> 6) & 15, l = s & 63;
    src = r1w + (ot * 16 + (l & 15)) * 512 + ks * 32 + (l >> 4) * 8;
    dst = w1p + s * 8;
  } else {
    int s = tid - 24576, ot = s >> 9, ks = (s >> 6) & 7, l = s & 63;
    src = r2w + (ot * 16 + (l & 15)) * 256 + ks * 32 + (l >> 4) * 8;
    dst = w2p + s * 8;
  }
  float4 v0 = *(const float4*)src;
  float4 v1 = *(const float4*)(src + 4);
  uint4 pk;
  pk.x = f2bf(v0.x) | (f2bf(v0.y) << 16);
  pk.y = f2bf(v0.z) | (f2bf(v0.w) << 16);
  pk.z = f2bf(v1.x) | (f2bf(v1.y) << 16);
  pk.w = f2bf(v1.z) | (f2bf(v1.w) << 16);
  *(uint4*)dst = pk;
}

// ---------------- y = mean(masked x, axis=(2,3)), float4 ----------------
__global__ void k_ymean(const float* __restrict__ x, const float* __restrict__ keep,
                        float* __restrict__ y) {
  int bc = blockIdx.x;
  int b = bc >> 8, c = bc & 255;
  const float4* row = (const float4*)(x + (size_t)bc * HW);
  int t = threadIdx.x;
  float s = 0.f;
  for (int q = t; q < HW / 4; q += 256) {
    float4 v = row[q];
    uint32_t base = (uint32_t)((b * HW + q * 4) * 256 + c);
    s += v.x * keep[base / 368u];
    s += v.y * keep[(base + 256u) / 368u];
    s += v.z * keep[(base + 512u) / 368u];
    s += v.w * keep[(base + 768u) / 368u];
  }
  for (int off = 32; off > 0; off >>= 1) s += __shfl_down(s, off);
  __shared__ float w4[4];
  if ((t & 63) == 0) w4[t >> 6] = s;
  __syncthreads();
  if (t == 0) y[bc] = (w4[0] + w4[1] + w4[2] + w4[3]) * (1.0f / HW);
}

// ---------------- scores -> per-(b,c) mask ----------------
__global__ void k_scores(const float* __restrict__ y, const float* __restrict__ fc1,
                         const float* __restrict__ fc2, const float* __restrict__ thr,
                         const float* __restrict__ aw, const int* __restrict__ plr,
                         float* __restrict__ maskv) {
  int b = blockIdx.x, t = threadIdx.x;
  __shared__ float ysh[256];
  __shared__ float hsh[16];
  ysh[t] = y[b * 256 + t];
  __syncthreads();
  if (t < 16) {
    float a = 0.f;
    for (int c = 0; c < 256; ++c) a += ysh[c] * fc1[t * 256 + c];
    hsh[t] = fmaxf(a, 0.f);
  }
  __syncthreads();
  float s = 0.f;
  #pragma unroll
  for (int j = 0; j < 16; ++j) s += hsh[j] * fc2[t * 16 + j];
  float sc = 1.f / (1.f + expf(-s));
  float m = sc + (float)plr[0] * aw[t] - thr[0];
  maskv[b * 256 + t] = fmaxf(m, 0.f);
}

// ---------------- fused main chain: bf16 MFMA (R6 partition, 3-barrier schedule) ----------------
// fragment-linear LDS: element (c,p) at ((c>>5)*4+(p>>4))*512 + ((p&15)+16*((c&31)>>3))*8 + (c&7)
// 8 waves, wave w = 2 ch-tiles (w*32..w*32+31) x all 64 px (4 B-frags/K-step).
// Phase order (3 barriers, was 4): rec1-partA (XT-only) moved BEFORE the ST barrier:
//   stage | B1 | det -> st->ST -> rec1a(XT) | B2 | rec1b(ST) -> r1->XT | B3 | rec2 -> epilogue
// Hazards: all XT-as-x reads (det, xv, rec1a) precede B2; r1-write after B2 conflicts with
// nothing (rec1b reads only ST); B3 publishes r1 for rec2. R9 tested this ordering but
// confounded it with a 4-A-stream fusion (regressed); this keeps R6's 2 A-streams.
// SESSION NOTES (measured): 2 A-streams/wave optimal (4 -> +20-30%, R5/R9); 64KB/2-blk
// residency optimal (reg-cap forcing spills, R7/R8); LDS-halving/occupancy-doubling neutral
// or worse (R5/R1). Balanced plateau LDS~41%/VALU~34%/MFMA~27%.
__global__ __launch_bounds__(512, 4) void k_main(
    const float* __restrict__ x, const float* __restrict__ keep,
    const ushort* __restrict__ wdp, const ushort* __restrict__ w1p,
    const ushort* __restrict__ w2p, const float* __restrict__ maskv,
    float* __restrict__ out) {
  __shared__ __align__(16) short XT[16384];   // 32 KB
  __shared__ __align__(16) short ST[16384];   // 32 KB
  int tile = blockIdx.x;
  int bb = tile / 49, hw0 = (tile % 49) * 64;
  int t = threadIdx.x;
  int lane = t & 63, w = t >> 6;
  int l15 = lane & 15, lhi = lane >> 4;

  // ---- stage masked x tile as bf16 fragments: wave w = channels w*32..w*32+31 ----
  {
    const float* xb = x + (size_t)bb * (Cch * HW);
    uint32_t pixb = (uint32_t)(bb * HW + hw0);
    int p = lane;
    uint32_t ia0 = (pixb + (uint32_t)p) * 256u;
    uint32_t k0 = ia0 / 368u;
    uint32_t cstar = 368u * (k0 + 1u) - ia0;   // channels >= cstar use chunk k0+1
    float kp0 = keep[k0];
    float kp1 = keep[k0 + 1];
    const float* xcol = xb + hw0 + p;
    int c0 = w * 32;
    #pragma unroll
    for (int k = 0; k < 4; ++k) {
      uint32_t pw0, pw1, pw2, pw3;
      #pragma unroll
      for (int h = 0; h < 4; ++h) {
        uint32_t ca = (uint32_t)(c0 + k * 8 + h * 2);
        float va = xcol[(size_t)ca * HW] * (ca < cstar ? kp0 : kp1);
        float vb = xcol[(size_t)(ca + 1u) * HW] * ((ca + 1u) < cstar ? kp0 : kp1);
        uint32_t pkv = cvtpk(va, vb);
        if (h == 0) pw0 = pkv; else if (h == 1) pw1 = pkv;
        else if (h == 2) pw2 = pkv; else pw3 = pkv;
      }
      uint4 pk; pk.x = pw0; pk.y = pw1; pk.z = pw2; pk.w = pw3;
      *(uint4*)&XT[(w * 4 + (p >> 4)) * 512 + ((p & 15) + 16 * k) * 8] = pk;
    }
  }
  __syncthreads();   // B1: x tile staged

  f32x4 zero4 = {0.f, 0.f, 0.f, 0.f};
  f32x4 acc[2][4];
  int row16a = (lhi >> 1);                // epilogue row helper
  int sub4 = (lhi & 1) * 4;

  // ======== det = Wd @ x ========
  #pragma unroll
  for (int mt = 0; mt < 2; ++mt)
    #pragma unroll
    for (int nt = 0; nt < 4; ++nt) acc[mt][nt] = zero4;
  {
    const ushort* a0p = wdp + ((w * 2 + 0) * 8) * 512 + lane * 8;
    const ushort* a1p = wdp + ((w * 2 + 1) * 8) * 512 + lane * 8;
    bf16x8 A0[8], A1[8];
    #pragma unroll
    for (int k = 0; k < 8; ++k) {
      A0[k] = *(const bf16x8*)(a0p + k * 512);
      A1[k] = *(const bf16x8*)(a1p + k * 512);
    }
    #pragma unroll
    for (int ks = 0; ks < 8; ++ks) {
      #pragma unroll
      for (int nt = 0; nt < 4; ++nt) {
        bf16x8 b = *(const bf16x8*)&XT[(ks * 4 + nt) * 512 + lane * 8];
        acc[0][nt] = __builtin_amdgcn_mfma_f32_16x16x32_bf16(A0[ks], b, acc[0][nt], 0, 0, 0);
        acc[1][nt] = __builtin_amdgcn_mfma_f32_16x16x32_bf16(A1[ks], b, acc[1][nt], 0, 0, 0);
      }
    }
  }

  // ---- st = sigmoid(det) * x -> ST (XT untouched; acc dies here) ----
  #pragma unroll
  for (int mt = 0; mt < 2; ++mt) {
    int row16 = mt * 2 + row16a;
    #pragma unroll
    for (int nt = 0; nt < 4; ++nt) {
      int off = (w * 4 + nt) * 512 + (l15 + 16 * row16) * 8 + sub4;
      ushort4 xv = *(const ushort4*)&XT[off];
      float s0 = bf2f(xv.x) / (1.f + __expf(-acc[mt][nt][0]));
      float s1 = bf2f(xv.y) / (1.f + __expf(-acc[mt][nt][1]));
      float s2 = bf2f(xv.z) / (1.f + __expf(-acc[mt][nt][2]));
      float s3 = bf2f(xv.w) / (1.f + __expf(-acc[mt][nt][3]));
      uint2 sv;
      sv.x = cvtpk(s0, s1);
      sv.y = cvtpk(s2, s3);
      *(uint2*)&ST[off] = sv;
    }
  }

  // ======== rec1 part A: W1[:,0:256] @ x (XT reads only; pre-barrier) ========
  f32x4 acc2[2][4];
  #pragma unroll
  for (int mt = 0; mt < 2; ++mt)
    #pragma unroll
    for (int nt = 0; nt < 4; ++nt) acc2[mt][nt] = zero4;
  {
    const ushort* a0p = w1p + ((w * 2 + 0) * 16) * 512 + lane * 8;
    const ushort* a1p = w1p + ((w * 2 + 1) * 16) * 512 + lane * 8;
    bf16x8 A0[8], A1[8];
    #pragma unroll
    for (int k = 0; k < 8; ++k) {
      A0[k] = *(const bf16x8*)(a0p + k * 512);
      A1[k] = *(const bf16x8*)(a1p + k * 512);
    }
    #pragma unroll
    for (int ks = 0; ks < 8; ++ks) {
      #pragma unroll
      for (int nt = 0; nt < 4; ++nt) {
        bf16x8 b = *(const bf16x8*)&XT[(ks * 4 + nt) * 512 + lane * 8];
        acc2[0][nt] = __builtin_amdgcn_mfma_f32_16x16x32_bf16(A0[ks], b, acc2[0][nt], 0, 0, 0);
        acc2[1][nt] = __builtin_amdgcn_mfma_f32_16x16x32_bf16(A1[ks], b, acc2[1][nt], 0, 0, 0);
      }
    }
  }
  __syncthreads();   // B2: ST visible; all XT-as-x reads (det/xv/rec1a) complete

  // ======== rec1 part B: acc2 += W1[:,256:512] @ st ========
  {
    const ushort* a0p = w1p + ((w * 2 + 0) * 16) * 512 + lane * 8;
    const ushort* a1p = w1p + ((w * 2 + 1) * 16) * 512 + lane * 8;
    bf16x8 A0[8], A1[8];
    #pragma unroll
    for (int k = 0; k < 8; ++k) {
      A0[k] = *(const bf16x8*)(a0p + (k + 8) * 512);
      A1[k] = *(const bf16x8*)(a1p + (k + 8) * 512);
    }
    #pragma unroll
    for (int ks = 0; ks < 8; ++ks) {
      #pragma unroll
      for (int nt = 0; nt < 4; ++nt) {
        bf16x8 b = *(const bf16x8*)&ST[(ks * 4 + nt) * 512 + lane * 8];
        acc2[0][nt] = __builtin_amdgcn_mfma_f32_16x16x32_bf16(A0[ks], b, acc2[0][nt], 0, 0, 0);
        acc2[1][nt] = __builtin_amdgcn_mfma_f32_16x16x32_bf16(A1[ks], b, acc2[1][nt], 0, 0, 0);
      }
    }
  }

  // ---- write r1 = relu(acc2) into XT (safe: only ST is being read by other waves) ----
  #pragma unroll
  for (int mt = 0; mt < 2; ++mt) {
    int row16 = mt * 2 + row16a;
    #pragma unroll
    for (int nt = 0; nt < 4; ++nt) {
      int off = (w * 4 + nt) * 512 + (l15 + 16 * row16) * 8 + sub4;
      uint2 rv;
      rv.x = cvtpk(fmaxf(acc2[mt][nt][0], 0.f), fmaxf(acc2[mt][nt][1], 0.f));
      rv.y = cvtpk(fmaxf(acc2[mt][nt][2], 0.f), fmaxf(acc2[mt][nt][3], 0.f));
      *(uint2*)&XT[off] = rv;
    }
  }
  __syncthreads();   // B3: r1 visible

  // ======== out = (W2 @ r1) * mask ========
  #pragma unroll
  for (int mt = 0; mt < 2; ++mt)
    #pragma unroll
    for (int nt = 0; nt < 4; ++nt) acc[mt][nt] = zero4;
  {
    const ushort* a0p = w2p + ((w * 2 + 0) * 8) * 512 + lane * 8;
    const ushort* a1p = w2p + ((w * 2 + 1) * 8) * 512 + lane * 8;
    bf16x8 A0[8], A1[8];
    #pragma unroll
    for (int k = 0; k < 8; ++k) {
      A0[k] = *(const bf16x8*)(a0p + k * 512);
      A1[k] = *(const bf16x8*)(a1p + k * 512);
    }
    #pragma unroll
    for (int ks = 0; ks < 8; ++ks) {
      #pragma unroll
      for (int nt = 0; nt < 4; ++nt) {
        bf16x8 b = *(const bf16x8*)&XT[(ks * 4 + nt) * 512 + lane * 8];
        acc[0][nt] = __builtin_amdgcn_mfma_f32_16x16x32_bf16(A0[ks], b, acc[0][nt], 0, 0, 0);
        acc[1][nt] = __builtin_amdgcn_mfma_f32_16x16x32_bf16(A1[ks], b, acc[1][nt], 0, 0, 0);
      }
    }
  }

  // ---- final: scale by mask, store fp32 ----
  #pragma unroll
  for (int mt = 0; mt < 2; ++mt)
    #pragma unroll
    for (int r = 0; r < 4; ++r) {
      int o = w * 32 + mt * 16 + 4 * lhi + r;
      float m = maskv[bb * 256 + o];
      float* orow = out + (size_t)(bb * 256 + o) * HW + hw0;
      #pragma unroll
      for (int nt = 0; nt < 4; ++nt)
        orow[nt * 16 + l15] = acc[mt][nt][r] * m;
    }
}

extern "C" void kernel_launch(void* const* d_in, const int* in_sizes, int n_in,
                              void* d_out, int out_size, void* d_ws, size_t ws_size,
                              hipStream_t stream) {
  const float* x   = (const float*)d_in[0];
  const float* fc1 = (const float*)d_in[1];
  const float* fc2 = (const float*)d_in[2];
  const float* thr = (const float*)d_in[3];
  const float* dw  = (const float*)d_in[4];
  const float* r1w = (const float*)d_in[5];
  const float* r2w = (const float*)d_in[6];
  const float* aw  = (const float*)d_in[7];
  const int*   plr = (const int*)d_in[8];

  float*    out = (float*)d_out;
  uint32_t* ob  = (uint32_t*)d_out;
  float*    ws  = (float*)d_ws;

  uint64_t* sc1   = (uint64_t*)(ob + SC1_W);
  uint64_t* sc2   = (uint64_t*)(ob + SC2_W);
  uint32_t* bits1 = ob + BITS1_W;
  uint32_t* bits2 = ob + BITS2_W;
  uint32_t* rk1   = ob + R1_W;
  uint32_t* rk2   = ob + R2_W;
  uint32_t* hist1 = ob + HIST1_W;
  uint32_t* pre1  = ob + PRE1_W;
  uint32_t* cnt1  = ob + CNT1_W;
  uint32_t* hist2 = ob + HIST2_W;
  uint32_t* pre2  = ob + PRE2_W;
  uint32_t* cnt2  = ob + CNT2_W;
  float*    yv    = (float*)(ob + Y_W);

  float*  keep  = ws + KEEP_W;
  float*  maskv = ws + MASKV_W;
  ushort* wdp   = (ushort*)(ws + WPACK_W);
  ushort* w1p   = wdp + 65536;
  ushort* w2p   = w1p + 131072;

  hipMemsetAsync((void*)(ob + HIST1_W), 0, (size_t)6 * NB2 * 4, stream);

  dim3 blk(256);
  k_bits<<<273, blk, 0, stream>>>(bits1, bits2, hist1, hist2);
  k_scan2<<<2, 1024, 0, stream>>>(hist1, pre1, hist2, pre2);
  k_scatter2<<<546, blk, 0, stream>>>(bits1, pre1, cnt1, sc1,
                                      bits2, pre2, cnt2, sc2);
  k_rank2<<<546, blk, 0, stream>>>(bits1, pre1, hist1, sc1, rk1,
                                   bits2, pre2, hist2, sc2, rk2);
  k_keepwpack<<<401, blk, 0, stream>>>(rk1, rk2, plr, keep, dw, r1w, r2w,
                                       wdp, w1p, w2p);
  k_ymean<<<8192, blk, 0, stream>>>(x, keep, yv);
  k_scores<<<32, blk, 0, stream>>>(yv, fc1, fc2, thr, aw, plr, maskv);
  k_main<<<1568, 512, 0, stream>>>(x, keep, wdp, w1p, w2p, maskv, out);
}

// Round 12
// 149.235 us; speedup vs baseline: 1.0193x; 1.0193x over previous
//
#include <hip/hip_runtime.h>
#include <stdint.h>

#define PARTITIONABLE 1

typedef float f32x4 __attribute__((ext_vector_type(4)));
typedef short bf16x8 __attribute__((ext_vector_type(8)));

namespace {
constexpr int Hh = 56, Ww = 56;
constexpr int HW = Hh * Ww;            // 3136
constexpr int Bsz = 32, Cch = 256;
constexpr int NCH = 69811;             // ceil(25690112*4/1472)
constexpr int HALF = 34906;
constexpr int NB2 = 4096;              // rank buckets (top 12 bits)

// ---- d_out scratch layout (u32 word offsets; consumed before final write) ----
constexpr int SC1_W   = 0;             // u64 x 69824
constexpr int SC2_W   = 139648;
constexpr int BITS1_W = 279296;
constexpr int BITS2_W = 349120;
constexpr int R1_W    = 418944;
constexpr int R2_W    = 488768;
constexpr int HIST1_W = 558592;        // 4096 each, 6 arrays contiguous
constexpr int PRE1_W  = 562688;
constexpr int CNT1_W  = 566784;
constexpr int HIST2_W = 570880;
constexpr int PRE2_W  = 574976;
constexpr int CNT2_W  = 579072;
constexpr int Y_W     = 583168;        // 8192 floats

// ---- d_ws layout ----
constexpr int KEEP_W  = 0;             // 69824 floats
constexpr int MASKV_W = 69824;         // 8192 floats
constexpr int WPACK_W = 78016;         // then bf16 packed weights (ushort)
}

// ---------------- threefry-2x32 (JAX-compatible) ----------------
__host__ __device__ constexpr uint32_t rotl32(uint32_t v, int r) {
  return (v << r) | (v >> (32 - r));
}
__host__ __device__ constexpr uint64_t tf2x32(uint32_t k0, uint32_t k1,
                                              uint32_t x0, uint32_t x1) {
  uint32_t ks2 = k0 ^ k1 ^ 0x1BD11BDAu;
  x0 += k0; x1 += k1;
  {const int R[4]={13,15,26,6};  for(int i=0;i<4;i++){x0+=x1;x1=rotl32(x1,R[i]);x1^=x0;}}
  x0 += k1;  x1 += ks2 + 1u;
  {const int R[4]={17,29,16,24}; for(int i=0;i<4;i++){x0+=x1;x1=rotl32(x1,R[i]);x1^=x0;}}
  x0 += ks2; x1 += k0 + 2u;
  {const int R[4]={13,15,26,6};  for(int i=0;i<4;i++){x0+=x1;x1=rotl32(x1,R[i]);x1^=x0;}}
  x0 += k0;  x1 += k1 + 3u;
  {const int R[4]={17,29,16,24}; for(int i=0;i<4;i++){x0+=x1;x1=rotl32(x1,R[i]);x1^=x0;}}
  x0 += k1;  x1 += ks2 + 4u;
  {const int R[4]={13,15,26,6};  for(int i=0;i<4;i++){x0+=x1;x1=rotl32(x1,R[i]);x1^=x0;}}
  x0 += ks2; x1 += k0 + 5u;
  return ((uint64_t)x0 << 32) | x1;
}

#if PARTITIONABLE
constexpr uint64_t KEY1 = tf2x32(0u, 1234u, 0u, 0u);
constexpr uint64_t SUB1 = tf2x32(0u, 1234u, 0u, 1u);
constexpr uint64_t SUB2 = tf2x32((uint32_t)(KEY1 >> 32), (uint32_t)KEY1, 0u, 1u);
constexpr uint32_t S1H = (uint32_t)(SUB1 >> 32), S1L = (uint32_t)SUB1;
constexpr uint32_t S2H = (uint32_t)(SUB2 >> 32), S2L = (uint32_t)SUB2;
#else
constexpr uint64_t E0 = tf2x32(0u, 1234u, 0u, 2u);
constexpr uint64_t E1 = tf2x32(0u, 1234u, 1u, 3u);
constexpr uint32_t K1H = (uint32_t)(E0 >> 32), K1L = (uint32_t)(E1 >> 32);
constexpr uint64_t F0 = tf2x32(K1H, K1L, 0u, 2u);
constexpr uint64_t F1 = tf2x32(K1H, K1L, 1u, 3u);
constexpr uint32_t S1H = (uint32_t)E0, S1L = (uint32_t)E1;
constexpr uint32_t S2H = (uint32_t)F0, S2L = (uint32_t)F1;
#endif

__device__ __forceinline__ uint32_t rnd_bits(uint32_t kh, uint32_t kl, uint32_t i) {
#if PARTITIONABLE
  uint64_t r = tf2x32(kh, kl, 0u, i);
  return (uint32_t)(r >> 32) ^ (uint32_t)r;
#else
  if (i < (uint32_t)HALF) {
    uint32_t x1 = (i + HALF < (uint32_t)NCH) ? i + HALF : 0u;
    return (uint32_t)(tf2x32(kh, kl, i, x1) >> 32);
  } else {
    return (uint32_t)tf2x32(kh, kl, i - HALF, i);
  }
#endif
}

// ---------------- bf16 helpers ----------------
__device__ __forceinline__ uint32_t f2bf(float f) {   // manual RNE (wpack path)
  uint32_t u = __float_as_uint(f);
  return (u + 0x7FFFu + ((u >> 16) & 1u)) >> 16;
}
__device__ __forceinline__ float bf2f(uint32_t h) {
  return __uint_as_float(h << 16);
}
// single-instruction packed f32x2 -> bf16x2 (RNE), gfx950
__device__ __forceinline__ uint32_t cvtpk(float lo, float hi) {
  uint32_t r;
  asm("v_cvt_pk_bf16_f32 %0, %1, %2" : "=v"(r) : "v"(lo), "v"(hi));
  return r;
}

// ---------------- mask pipeline ----------------
__global__ void k_bits(uint32_t* bits1, uint32_t* bits2,
                       uint32_t* hist1, uint32_t* hist2) {
  int i = blockIdx.x * 256 + threadIdx.x;
  if (i >= NCH) return;
  uint32_t b1 = rnd_bits(S1H, S1L, (uint32_t)i);
  uint32_t b2 = rnd_bits(S2H, S2L, (uint32_t)i);
  bits1[i] = b1; bits2[i] = b2;
  atomicAdd(&hist1[b1 >> 20], 1u);
  atomicAdd(&hist2[b2 >> 20], 1u);
}

// both scans in one launch: block 0 -> (h1,p1), block 1 -> (h2,p2)
__global__ __launch_bounds__(1024) void k_scan2(const uint32_t* h1, uint32_t* p1o,
                                                const uint32_t* h2, uint32_t* p2o) {
  const uint32_t* h = blockIdx.x ? h2 : h1;
  uint32_t* pre = blockIdx.x ? p2o : p1o;
  __shared__ uint32_t part[1024];
  int t = threadIdx.x;
  uint4 v = *(const uint4*)&h[t * 4];
  uint32_t s = v.x + v.y + v.z + v.w;
  part[t] = s;
  __syncthreads();
  for (int off = 1; off < 1024; off <<= 1) {
    uint32_t u = (t >= off) ? part[t - off] : 0u;
    __syncthreads();
    part[t] += u;
    __syncthreads();
  }
  uint32_t run = part[t] - s;
  uint4 o;
  o.x = run; o.y = run + v.x; o.z = o.y + v.y; o.w = o.z + v.z;
  *(uint4*)&pre[t * 4] = o;
}

__global__ void k_scatter2(const uint32_t* bits1, const uint32_t* pre1,
                           uint32_t* cnt1, uint64_t* sc1,
                           const uint32_t* bits2, const uint32_t* pre2,
                           uint32_t* cnt2, uint64_t* sc2) {
  int blk = blockIdx.x;
  bool second = blk >= 273;
  const uint32_t* bits = second ? bits2 : bits1;
  const uint32_t* pre  = second ? pre2  : pre1;
  uint32_t* cnt = second ? cnt2 : cnt1;
  uint64_t* sc  = second ? sc2  : sc1;
  int i = (second ? blk - 273 : blk) * 256 + threadIdx.x;
  if (i >= NCH) return;
  uint32_t b = bits[i], bk = b >> 20;
  uint32_t pos = pre[bk] + atomicAdd(&cnt[bk], 1u);
  sc[pos] = ((uint64_t)b << 32) | (uint32_t)i;
}

__global__ void k_rank2(const uint32_t* bits1, const uint32_t* pre1,
                        const uint32_t* hist1, const uint64_t* sc1, uint32_t* rk1,
                        const uint32_t* bits2, const uint32_t* pre2,
                        const uint32_t* hist2, const uint64_t* sc2, uint32_t* rk2) {
  int blk = blockIdx.x;
  bool second = blk >= 273;
  const uint32_t* bits = second ? bits2 : bits1;
  const uint32_t* pre  = second ? pre2  : pre1;
  const uint32_t* hist = second ? hist2 : hist1;
  const uint64_t* sc   = second ? sc2   : sc1;
  uint32_t* rnk = second ? rk2 : rk1;
  int i = (second ? blk - 273 : blk) * 256 + threadIdx.x;
  if (i >= NCH) return;
  uint32_t b = bits[i], bk = b >> 20;
  uint32_t s = pre[bk], n = hist[bk];
  uint64_t my = ((uint64_t)b << 32) | (uint32_t)i;
  uint32_t c = 0;
  for (uint32_t k = 0; k < n; ++k) c += (sc[s + k] < my) ? 1u : 0u;
  rnk[i] = s + c;
}

// keep + weight prepack fused (wpack part has no deps on rank)
__global__ void k_keepwpack(const uint32_t* r1, const uint32_t* r2,
                            const int* plr, float* keep,
                            const float* __restrict__ dw,
                            const float* __restrict__ r1w,
                            const float* __restrict__ r2w,
                            ushort* __restrict__ wdp, ushort* __restrict__ w1p,
                            ushort* __restrict__ w2p) {
  int blk = blockIdx.x;
  if (blk < 273) {
    int j = blk * 256 + threadIdx.x;
    if (j >= NCH) return;
    int L = (NCH * plr[0] + 99) / 100;
    keep[j] = (r2[r1[j]] < (uint32_t)L) ? 0.f : 1.f;
    return;
  }
  int tid = (blk - 273) * 256 + threadIdx.x;   // 32768 slots
  const float* src;
  ushort* dst;
  if (tid < 8192) {
    int s = tid, ot = s >> 9, ks = (s >> 6) & 7, l = s & 63;
    src = dw + (ot * 16 + (l & 15)) * 256 + ks * 32 + (l >> 4) * 8;
    dst = wdp + s * 8;
  } else if (tid < 24576) {
    int s = tid - 8192, ot = s >> 10, ks = (s >> 6) & 15, l = s & 63;
    src = r1w + (ot * 16 + (l & 15)) * 512 + ks * 32 + (l >> 4) * 8;
    dst = w1p + s * 8;
  } else {
    int s = tid - 24576, ot = s >> 9, ks = (s >> 6) & 7, l = s & 63;
    src = r2w + (ot * 16 + (l & 15)) * 256 + ks * 32 + (l >> 4) * 8;
    dst = w2p + s * 8;
  }
  float4 v0 = *(const float4*)src;
  float4 v1 = *(const float4*)(src + 4);
  uint4 pk;
  pk.x = f2bf(v0.x) | (f2bf(v0.y) << 16);
  pk.y = f2bf(v0.z) | (f2bf(v0.w) << 16);
  pk.z = f2bf(v1.x) | (f2bf(v1.y) << 16);
  pk.w = f2bf(v1.z) | (f2bf(v1.w) << 16);
  *(uint4*)dst = pk;
}

// ---------------- y = mean(masked x, axis=(2,3)), float4 ----------------
__global__ void k_ymean(const float* __restrict__ x, const float* __restrict__ keep,
                        float* __restrict__ y) {
  int bc = blockIdx.x;
  int b = bc >> 8, c = bc & 255;
  const float4* row = (const float4*)(x + (size_t)bc * HW);
  int t = threadIdx.x;
  float s = 0.f;
  for (int q = t; q < HW / 4; q += 256) {
    float4 v = row[q];
    uint32_t base = (uint32_t)((b * HW + q * 4) * 256 + c);
    s += v.x * keep[base / 368u];
    s += v.y * keep[(base + 256u) / 368u];
    s += v.z * keep[(base + 512u) / 368u];
    s += v.w * keep[(base + 768u) / 368u];
  }
  for (int off = 32; off > 0; off >>= 1) s += __shfl_down(s, off);
  __shared__ float w4[4];
  if ((t & 63) == 0) w4[t >> 6] = s;
  __syncthreads();
  if (t == 0) y[bc] = (w4[0] + w4[1] + w4[2] + w4[3]) * (1.0f / HW);
}

// ---------------- scores -> per-(b,c) mask ----------------
__global__ void k_scores(const float* __restrict__ y, const float* __restrict__ fc1,
                         const float* __restrict__ fc2, const float* __restrict__ thr,
                         const float* __restrict__ aw, const int* __restrict__ plr,
                         float* __restrict__ maskv) {
  int b = blockIdx.x, t = threadIdx.x;
  __shared__ float ysh[256];
  __shared__ float hsh[16];
  ysh[t] = y[b * 256 + t];
  __syncthreads();
  if (t < 16) {
    float a = 0.f;
    for (int c = 0; c < 256; ++c) a += ysh[c] * fc1[t * 256 + c];
    hsh[t] = fmaxf(a, 0.f);
  }
  __syncthreads();
  float s = 0.f;
  #pragma unroll
  for (int j = 0; j < 16; ++j) s += hsh[j] * fc2[t * 16 + j];
  float sc = 1.f / (1.f + expf(-s));
  float m = sc + (float)plr[0] * aw[t] - thr[0];
  maskv[b * 256 + t] = fmaxf(m, 0.f);
}

// ---------------- fused main chain: bf16 MFMA (best-measured configuration, FINAL) ----------------
// fragment-linear LDS: element (c,p) at ((c>>5)*4+(p>>4))*512 + ((p&15)+16*((c&31)>>3))*8 + (c&7)
// 8 waves, wave w = 2 ch-tiles (w*32..w*32+31) x all 64 px (4 B-frags/K-step), 4 barriers.
// SESSION LEDGER (all measured, k_main dur):
//  - THIS config: 77.0-77.3us, VGPR 52, MfmaUtil ~27.5, Occ ~34.5 (R6/R10).
//  - 2x occupancy (1024thr, 1 tile/wave):          84us  (R1)
//  - 32x32 MFMA, 1/4 LDS traffic, 4 waves:        109us  (R2)
//  - cooperative grid.sync fusion:        +115us/barrier  (R3)
//  - __threadfence arrival fusion:              +150us    (R4)
//  - 4ch x 2px repartition (4 A-streams):          94us   (R5)
//  - 32KB LDS + reg caps (6 or 4 waves/EU):  spills: 290/92us (R7/R8)
//  - det/rec1a B-share fusion (4 A-streams):      103us   (R9)
//  - 3-barrier reorder (2 A-streams):              80us   (R11)
// Conclusion: balanced plateau (LDS~41%/VALU~34%/MFMA~27%/HBM~26%, none saturated),
// barrier-serialized at 2 blk/CU; 2 global A-streams/wave is optimal; all source-level
// perturbations regress. Structural floor for this schedule family.
__global__ __launch_bounds__(512, 4) void k_main(
    const float* __restrict__ x, const float* __restrict__ keep,
    const ushort* __restrict__ wdp, const ushort* __restrict__ w1p,
    const ushort* __restrict__ w2p, const float* __restrict__ maskv,
    float* __restrict__ out) {
  __shared__ __align__(16) short XT[16384];   // 32 KB
  __shared__ __align__(16) short ST[16384];   // 32 KB
  int tile = blockIdx.x;
  int bb = tile / 49, hw0 = (tile % 49) * 64;
  int t = threadIdx.x;
  int lane = t & 63, w = t >> 6;
  int l15 = lane & 15, lhi = lane >> 4;

  // ---- stage masked x tile as bf16 fragments: wave w = channels w*32..w*32+31 ----
  {
    const float* xb = x + (size_t)bb * (Cch * HW);
    uint32_t pixb = (uint32_t)(bb * HW + hw0);
    int p = lane;
    uint32_t ia0 = (pixb + (uint32_t)p) * 256u;
    uint32_t k0 = ia0 / 368u;
    uint32_t cstar = 368u * (k0 + 1u) - ia0;   // channels >= cstar use chunk k0+1
    float kp0 = keep[k0];
    float kp1 = keep[k0 + 1];
    const float* xcol = xb + hw0 + p;
    int c0 = w * 32;
    #pragma unroll
    for (int k = 0; k < 4; ++k) {
      uint32_t pw0, pw1, pw2, pw3;
      #pragma unroll
      for (int h = 0; h < 4; ++h) {
        uint32_t ca = (uint32_t)(c0 + k * 8 + h * 2);
        float va = xcol[(size_t)ca * HW] * (ca < cstar ? kp0 : kp1);
        float vb = xcol[(size_t)(ca + 1u) * HW] * ((ca + 1u) < cstar ? kp0 : kp1);
        uint32_t pkv = cvtpk(va, vb);
        if (h == 0) pw0 = pkv; else if (h == 1) pw1 = pkv;
        else if (h == 2) pw2 = pkv; else pw3 = pkv;
      }
      uint4 pk; pk.x = pw0; pk.y = pw1; pk.z = pw2; pk.w = pw3;
      *(uint4*)&XT[(w * 4 + (p >> 4)) * 512 + ((p & 15) + 16 * k) * 8] = pk;
    }
  }
  __syncthreads();

  f32x4 zero4 = {0.f, 0.f, 0.f, 0.f};
  f32x4 acc[2][4];
  int row16a = (lhi >> 1);                // epilogue row helper
  int sub4 = (lhi & 1) * 4;

  // ======== det = Wd @ x ========
  #pragma unroll
  for (int mt = 0; mt < 2; ++mt)
    #pragma unroll
    for (int nt = 0; nt < 4; ++nt) acc[mt][nt] = zero4;
  {
    const ushort* a0p = wdp + ((w * 2 + 0) * 8) * 512 + lane * 8;
    const ushort* a1p = wdp + ((w * 2 + 1) * 8) * 512 + lane * 8;
    bf16x8 A0[8], A1[8];
    #pragma unroll
    for (int k = 0; k < 8; ++k) {
      A0[k] = *(const bf16x8*)(a0p + k * 512);
      A1[k] = *(const bf16x8*)(a1p + k * 512);
    }
    #pragma unroll
    for (int ks = 0; ks < 8; ++ks) {
      #pragma unroll
      for (int nt = 0; nt < 4; ++nt) {
        bf16x8 b = *(const bf16x8*)&XT[(ks * 4 + nt) * 512 + lane * 8];
        acc[0][nt] = __builtin_amdgcn_mfma_f32_16x16x32_bf16(A0[ks], b, acc[0][nt], 0, 0, 0);
        acc[1][nt] = __builtin_amdgcn_mfma_f32_16x16x32_bf16(A1[ks], b, acc[1][nt], 0, 0, 0);
      }
    }
  }

  // ---- st = sigmoid(det) * x  (XT untouched; no barrier needed) ----
  #pragma unroll
  for (int mt = 0; mt < 2; ++mt) {
    int row16 = mt * 2 + row16a;
    #pragma unroll
    for (int nt = 0; nt < 4; ++nt) {
      int off = (w * 4 + nt) * 512 + (l15 + 16 * row16) * 8 + sub4;
      ushort4 xv = *(const ushort4*)&XT[off];
      float s0 = bf2f(xv.x) / (1.f + __expf(-acc[mt][nt][0]));
      float s1 = bf2f(xv.y) / (1.f + __expf(-acc[mt][nt][1]));
      float s2 = bf2f(xv.z) / (1.f + __expf(-acc[mt][nt][2]));
      float s3 = bf2f(xv.w) / (1.f + __expf(-acc[mt][nt][3]));
      uint2 sv;
      sv.x = cvtpk(s0, s1);
      sv.y = cvtpk(s2, s3);
      *(uint2*)&ST[off] = sv;
    }
  }
  __syncthreads();

  // ======== r1 = relu(W1 @ [x; st]) ======== (two 16-fragment A batches)
  f32x4 acc2[2][4];
  #pragma unroll
  for (int mt = 0; mt < 2; ++mt)
    #pragma unroll
    for (int nt = 0; nt < 4; ++nt) acc2[mt][nt] = zero4;
  {
    const ushort* a0p = w1p + ((w * 2 + 0) * 16) * 512 + lane * 8;
    const ushort* a1p = w1p + ((w * 2 + 1) * 16) * 512 + lane * 8;
    bf16x8 A0[8], A1[8];
    // half 1: ks 0..7 (B from XT)
    #pragma unroll
    for (int k = 0; k < 8; ++k) {
      A0[k] = *(const bf16x8*)(a0p + k * 512);
      A1[k] = *(const bf16x8*)(a1p + k * 512);
    }
    #pragma unroll
    for (int ks = 0; ks < 8; ++ks) {
      #pragma unroll
      for (int nt = 0; nt < 4; ++nt) {
        bf16x8 b = *(const bf16x8*)&XT[(ks * 4 + nt) * 512 + lane * 8];
        acc2[0][nt] = __builtin_amdgcn_mfma_f32_16x16x32_bf16(A0[ks], b, acc2[0][nt], 0, 0, 0);
        acc2[1][nt] = __builtin_amdgcn_mfma_f32_16x16x32_bf16(A1[ks], b, acc2[1][nt], 0, 0, 0);
      }
    }
    // half 2: ks 8..15 (B from ST)
    #pragma unroll
    for (int k = 0; k < 8; ++k) {
      A0[k] = *(const bf16x8*)(a0p + (k + 8) * 512);
      A1[k] = *(const bf16x8*)(a1p + (k + 8) * 512);
    }
    #pragma unroll
    for (int ks = 0; ks < 8; ++ks) {
      #pragma unroll
      for (int nt = 0; nt < 4; ++nt) {
        bf16x8 b = *(const bf16x8*)&ST[(ks * 4 + nt) * 512 + lane * 8];
        acc2[0][nt] = __builtin_amdgcn_mfma_f32_16x16x32_bf16(A0[ks], b, acc2[0][nt], 0, 0, 0);
        acc2[1][nt] = __builtin_amdgcn_mfma_f32_16x16x32_bf16(A1[ks], b, acc2[1][nt], 0, 0, 0);
      }
    }
  }
  __syncthreads();   // all rec1 LDS reads complete before overwriting XT

  // ---- write r1 = relu(acc2) into XT ----
  #pragma unroll
  for (int mt = 0; mt < 2; ++mt) {
    int row16 = mt * 2 + row16a;
    #pragma unroll
    for (int nt = 0; nt < 4; ++nt) {
      int off = (w * 4 + nt) * 512 + (l15 + 16 * row16) * 8 + sub4;
      uint2 rv;
      rv.x = cvtpk(fmaxf(acc2[mt][nt][0], 0.f), fmaxf(acc2[mt][nt][1], 0.f));
      rv.y = cvtpk(fmaxf(acc2[mt][nt][2], 0.f), fmaxf(acc2[mt][nt][3], 0.f));
      *(uint2*)&XT[off] = rv;
    }
  }
  __syncthreads();

  // ======== out = (W2 @ r1) * mask ========
  #pragma unroll
  for (int mt = 0; mt < 2; ++mt)
    #pragma unroll
    for (int nt = 0; nt < 4; ++nt) acc[mt][nt] = zero4;
  {
    const ushort* a0p = w2p + ((w * 2 + 0) * 8) * 512 + lane * 8;
    const ushort* a1p = w2p + ((w * 2 + 1) * 8) * 512 + lane * 8;
    bf16x8 A0[8], A1[8];
    #pragma unroll
    for (int k = 0; k < 8; ++k) {
      A0[k] = *(const bf16x8*)(a0p + k * 512);
      A1[k] = *(const bf16x8*)(a1p + k * 512);
    }
    #pragma unroll
    for (int ks = 0; ks < 8; ++ks) {
      #pragma unroll
      for (int nt = 0; nt < 4; ++nt) {
        bf16x8 b = *(const bf16x8*)&XT[(ks * 4 + nt) * 512 + lane * 8];
        acc[0][nt] = __builtin_amdgcn_mfma_f32_16x16x32_bf16(A0[ks], b, acc[0][nt], 0, 0, 0);
        acc[1][nt] = __builtin_amdgcn_mfma_f32_16x16x32_bf16(A1[ks], b, acc[1][nt], 0, 0, 0);
      }
    }
  }

  // ---- final: scale by mask, store fp32 ----
  #pragma unroll
  for (int mt = 0; mt < 2; ++mt)
    #pragma unroll
    for (int r = 0; r < 4; ++r) {
      int o = w * 32 + mt * 16 + 4 * lhi + r;
      float m = maskv[bb * 256 + o];
      float* orow = out + (size_t)(bb * 256 + o) * HW + hw0;
      #pragma unroll
      for (int nt = 0; nt < 4; ++nt)
        orow[nt * 16 + l15] = acc[mt][nt][r] * m;
    }
}

extern "C" void kernel_launch(void* const* d_in, const int* in_sizes, int n_in,
                              void* d_out, int out_size, void* d_ws, size_t ws_size,
                              hipStream_t stream) {
  const float* x   = (const float*)d_in[0];
  const float* fc1 = (const float*)d_in[1];
  const float* fc2 = (const float*)d_in[2];
  const float* thr = (const float*)d_in[3];
  const float* dw  = (const float*)d_in[4];
  const float* r1w = (const float*)d_in[5];
  const float* r2w = (const float*)d_in[6];
  const float* aw  = (const float*)d_in[7];
  const int*   plr = (const int*)d_in[8];

  float*    out = (float*)d_out;
  uint32_t* ob  = (uint32_t*)d_out;
  float*    ws  = (float*)d_ws;

  uint64_t* sc1   = (uint64_t*)(ob + SC1_W);
  uint64_t* sc2   = (uint64_t*)(ob + SC2_W);
  uint32_t* bits1 = ob + BITS1_W;
  uint32_t* bits2 = ob + BITS2_W;
  uint32_t* rk1   = ob + R1_W;
  uint32_t* rk2   = ob + R2_W;
  uint32_t* hist1 = ob + HIST1_W;
  uint32_t* pre1  = ob + PRE1_W;
  uint32_t* cnt1  = ob + CNT1_W;
  uint32_t* hist2 = ob + HIST2_W;
  uint32_t* pre2  = ob + PRE2_W;
  uint32_t* cnt2  = ob + CNT2_W;
  float*    yv    = (float*)(ob + Y_W);

  float*  keep  = ws + KEEP_W;
  float*  maskv = ws + MASKV_W;
  ushort* wdp   = (ushort*)(ws + WPACK_W);
  ushort* w1p   = wdp + 65536;
  ushort* w2p   = w1p + 131072;

  hipMemsetAsync((void*)(ob + HIST1_W), 0, (size_t)6 * NB2 * 4, stream);

  dim3 blk(256);
  k_bits<<<273, blk, 0, stream>>>(bits1, bits2, hist1, hist2);
  k_scan2<<<2, 1024, 0, stream>>>(hist1, pre1, hist2, pre2);
  k_scatter2<<<546, blk, 0, stream>>>(bits1, pre1, cnt1, sc1,
                                      bits2, pre2, cnt2, sc2);
  k_rank2<<<546, blk, 0, stream>>>(bits1, pre1, hist1, sc1, rk1,
                                   bits2, pre2, hist2, sc2, rk2);
  k_keepwpack<<<401, blk, 0, stream>>>(rk1, rk2, plr, keep, dw, r1w, r2w,
                                       wdp, w1p, w2p);
  k_ymean<<<8192, blk, 0, stream>>>(x, keep, yv);
  k_scores<<<32, blk, 0, stream>>>(yv, fc1, fc2, thr, aw, plr, maskv);
  k_main<<<1568, 512, 0, stream>>>(x, keep, wdp, w1p, w2p, maskv, out);
}